// Round 2
// baseline (1112.015 us; speedup 1.0000x reference)
//
#include <hip/hip_runtime.h>
#include <math.h>

static constexpr int N = 100000;
static constexpr int NB = (N + 255) / 256;   // 391 blocks over nodes

// ---------------- CSR build ----------------
__global__ void k_zero(int* __restrict__ p, int n) {
    int i = blockIdx.x * blockDim.x + threadIdx.x;
    if (i < n) p[i] = 0;
}

__global__ void k_count(const int* __restrict__ dst, int* __restrict__ cnt, int E) {
    int e = blockIdx.x * blockDim.x + threadIdx.x;
    if (e < E) atomicAdd(cnt + dst[e], 1);
}

__global__ __launch_bounds__(256) void k_scan1(const int* __restrict__ cnt, int* __restrict__ bsum) {
    __shared__ int s[256];
    const int t = threadIdx.x;
    const int i = blockIdx.x * 256 + t;
    s[t] = (i < N) ? cnt[i] : 0;
    __syncthreads();
    for (int off = 128; off > 0; off >>= 1) {
        if (t < off) s[t] += s[t + off];
        __syncthreads();
    }
    if (t == 0) bsum[blockIdx.x] = s[0];
}

__global__ __launch_bounds__(512) void k_scan2(const int* __restrict__ bsum, int* __restrict__ boff, int nb) {
    __shared__ int s[512];
    const int t = threadIdx.x;
    s[t] = (t < nb) ? bsum[t] : 0;
    __syncthreads();
    for (int off = 1; off < 512; off <<= 1) {
        int v = (t >= off) ? s[t - off] : 0;
        __syncthreads();
        s[t] += v;
        __syncthreads();
    }
    if (t < nb) boff[t] = (t == 0) ? 0 : s[t - 1];
}

__global__ __launch_bounds__(256) void k_scan3(const int* __restrict__ cnt, const int* __restrict__ boff,
                                               int* __restrict__ row_start, int* __restrict__ cursor) {
    __shared__ int s[256];
    const int t = threadIdx.x;
    const int i = blockIdx.x * 256 + t;
    const int v = (i < N) ? cnt[i] : 0;
    s[t] = v;
    __syncthreads();
    for (int off = 1; off < 256; off <<= 1) {
        int u = (t >= off) ? s[t - off] : 0;
        __syncthreads();
        s[t] += u;
        __syncthreads();
    }
    if (i < N) {
        int excl = s[t] - v + boff[blockIdx.x];
        row_start[i] = excl;
        cursor[i] = excl;
    }
}

__global__ void k_fill(const int* __restrict__ src, const int* __restrict__ dst,
                       int* __restrict__ cursor, int* __restrict__ col, int E) {
    int e = blockIdx.x * blockDim.x + threadIdx.x;
    if (e < E) {
        int p = atomicAdd(cursor + dst[e], 1);
        col[p] = src[e];
    }
}

// ---------------- layer 1 transform: g1 = dis * (x @ W1^T) ----------------
// x: [N,128], W1: [32,128]. 8 nodes per 256-thread block; thread = (node_local<<5)|j.
__global__ __launch_bounds__(256) void k_xw1(
        const float* __restrict__ x, const float* __restrict__ W1,
        const int* __restrict__ cnt, float* __restrict__ g1) {
    __shared__ float wt[128 * 33];   // W1 transposed [k][j], pad 33
    __shared__ float xs[8 * 128];
    const int t = threadIdx.x;
    for (int idx = t; idx < 4096; idx += 256) {
        int j = idx >> 7, k = idx & 127;
        wt[k * 33 + j] = W1[idx];
    }
    const float4* x4 = (const float4*)x + (size_t)blockIdx.x * 256;
    ((float4*)xs)[t] = x4[t];
    __syncthreads();

    const int nl = t >> 5, j = t & 31;
    const int node = blockIdx.x * 8 + nl;
    const float* xr = xs + nl * 128;
    float a = 0.f;
#pragma unroll 8
    for (int k = 0; k < 128; ++k) a = fmaf(xr[k], wt[k * 33 + j], a);
    g1[blockIdx.x * 256 + t] = a * rsqrtf((float)(cnt[node] + 1));
}

// ---------------- gather layer 1: h1 = relu(dis*(sum_in g1[src] + g1[node]) + b1) ----------------
// 8 nodes / 256-thread block, 32 lanes per node (half-wave).
__global__ __launch_bounds__(256) void k_gather1(
        const int* __restrict__ row_start, const int* __restrict__ cnt,
        const int* __restrict__ col, const float* __restrict__ g1,
        const float* __restrict__ b1, float* __restrict__ h1) {
    const int t = threadIdx.x;
    const int node = blockIdx.x * 8 + (t >> 5);
    const int j = t & 31;
    const int rs = row_start[node];
    const int ne = cnt[node];
    float sum = g1[node * 32 + j];     // self-loop term
    for (int base = 0; base < ne; base += 32) {
        int e = base + j;
        int s = (e < ne) ? col[rs + e] : 0;
        int m = (ne - base < 32) ? (ne - base) : 32;
        for (int k = 0; k < m; ++k) {
            int sk = __shfl(s, k, 32);
            sum += g1[sk * 32 + j];
        }
    }
    float v = sum * rsqrtf((float)(ne + 1)) + b1[j];
    h1[node * 32 + j] = v > 0.f ? v : 0.f;
}

// ---------------- layer 2 transform: g2 = dis * (h1 @ W2^T) ----------------
// 16 nodes per block; thread = (node_local<<4)|j.
__global__ __launch_bounds__(256) void k_layer2(
        const float* __restrict__ h1, const float* __restrict__ W2,
        const int* __restrict__ cnt, float* __restrict__ g2) {
    __shared__ float h1s[16 * 32];
    __shared__ float w2t[32 * 17];
    const int t = threadIdx.x;
    for (int idx = t; idx < 512; idx += 256) {
        int j = idx >> 5, k = idx & 31;
        w2t[k * 17 + j] = W2[idx];
    }
    const int base = blockIdx.x * 512;
    for (int idx = t; idx < 512; idx += 256) h1s[idx] = h1[base + idx];
    __syncthreads();
    const int nl = t >> 4, j = t & 15;
    const int node = blockIdx.x * 16 + nl;
    const float* hr = h1s + nl * 32;
    float a = 0.f;
#pragma unroll
    for (int k = 0; k < 32; ++k) a = fmaf(hr[k], w2t[k * 17 + j], a);
    g2[blockIdx.x * 256 + t] = a * rsqrtf((float)(cnt[node] + 1));
}

// ---------------- gather layer 2 + LSTM + head, fused ----------------
// 16 nodes / 256-thread block, 16 lanes per node (quarter-wave).
__global__ __launch_bounds__(256) void k_gather2(
        const int* __restrict__ row_start, const int* __restrict__ cnt,
        const int* __restrict__ col, const float* __restrict__ g2,
        const float* __restrict__ b2,
        const float* __restrict__ w_ih, const float* __restrict__ b_ih,
        const float* __restrict__ b_hh, const float* __restrict__ W_out,
        const float* __restrict__ b_out, float* __restrict__ out) {
    __shared__ float h2s[16 * 17];
    __shared__ float wih[512];
    __shared__ float bias[32];
    __shared__ float wout[8];
    __shared__ float bo;
    const int t = threadIdx.x;
    for (int idx = t; idx < 512; idx += 256) wih[idx] = w_ih[idx];
    if (t < 32) bias[t] = b_ih[t] + b_hh[t];
    if (t < 8)  wout[t] = W_out[t];
    if (t == 0) bo = b_out[0];

    const int nl = t >> 4, j = t & 15;
    const int node = blockIdx.x * 16 + nl;
    const int rs = row_start[node];
    const int ne = cnt[node];
    float sum = g2[node * 16 + j];     // self-loop term
    for (int base = 0; base < ne; base += 16) {
        int e = base + j;
        int s = (e < ne) ? col[rs + e] : 0;
        int m = (ne - base < 16) ? (ne - base) : 16;
        for (int k = 0; k < m; ++k) {
            int sk = __shfl(s, k, 16);
            sum += g2[sk * 16 + j];
        }
    }
    float v = sum * rsqrtf((float)(ne + 1)) + b2[j];
    h2s[nl * 17 + j] = v > 0.f ? v : 0.f;
    __syncthreads();

    if (t < 16) {
        const float* h2 = h2s + t * 17;
        float oacc = 0.f;
#pragma unroll
        for (int q = 0; q < 8; ++q) {
            float gi = bias[q], gg = bias[16 + q], go = bias[24 + q];
#pragma unroll
            for (int k = 0; k < 16; ++k) {
                gi = fmaf(h2[k], wih[q * 16 + k], gi);
                gg = fmaf(h2[k], wih[(16 + q) * 16 + k], gg);
                go = fmaf(h2[k], wih[(24 + q) * 16 + k], go);
            }
            float c  = (1.f / (1.f + expf(-gi))) * tanhf(gg);
            float hh = (1.f / (1.f + expf(-go))) * tanhf(c);
            oacc = fmaf(hh, wout[q], oacc);
        }
        out[blockIdx.x * 16 + t] = oacc + bo;
    }
}

extern "C" void kernel_launch(void* const* d_in, const int* in_sizes, int n_in,
                              void* d_out, int out_size, void* d_ws, size_t ws_size,
                              hipStream_t stream) {
    const float* x     = (const float*)d_in[0];
    const int*   ei    = (const int*)d_in[1];
    const float* W1    = (const float*)d_in[2];
    const float* b1    = (const float*)d_in[3];
    const float* W2    = (const float*)d_in[4];
    const float* b2    = (const float*)d_in[5];
    const float* w_ih  = (const float*)d_in[6];
    // d_in[7] = w_hh: unused (h0 = 0)
    const float* b_ih  = (const float*)d_in[8];
    const float* b_hh  = (const float*)d_in[9];
    const float* W_out = (const float*)d_in[10];
    const float* b_out = (const float*)d_in[11];
    float* out = (float*)d_out;

    const int E = in_sizes[1] / 2;
    const int* src = ei;
    const int* dst = ei + E;

    int* cnt       = (int*)d_ws;           // N
    int* row_start = cnt + N;              // N
    int* cursor    = row_start + N;        // N
    int* bsum      = cursor + N;           // 512
    int* boff      = bsum + 512;           // 512
    int* col       = boff + 512;           // E
    float* g1      = (float*)(col + E);    // N*32
    float* h1      = g1 + (size_t)N * 32;  // N*32
    float* g2      = g1;                   // overlay (g1 dead after k_gather1)

    k_zero   <<<NB, 256, 0, stream>>>(cnt, N);
    k_count  <<<(E + 255) / 256, 256, 0, stream>>>(dst, cnt, E);
    k_scan1  <<<NB, 256, 0, stream>>>(cnt, bsum);
    k_scan2  <<<1, 512, 0, stream>>>(bsum, boff, NB);
    k_scan3  <<<NB, 256, 0, stream>>>(cnt, boff, row_start, cursor);
    k_fill   <<<(E + 255) / 256, 256, 0, stream>>>(src, dst, cursor, col, E);
    k_xw1    <<<N / 8, 256, 0, stream>>>(x, W1, cnt, g1);
    k_gather1<<<N / 8, 256, 0, stream>>>(row_start, cnt, col, g1, b1, h1);
    k_layer2 <<<N / 16, 256, 0, stream>>>(h1, W2, cnt, g2);
    k_gather2<<<N / 16, 256, 0, stream>>>(row_start, cnt, col, g2, b2,
                                          w_ih, b_ih, b_hh, W_out, b_out, out);
}

// Round 3
// 644.623 us; speedup vs baseline: 1.7251x; 1.7251x over previous
//
#include <hip/hip_runtime.h>
#include <math.h>

static constexpr int N = 100000;
static constexpr int NB = (N + 255) / 256;   // 391 blocks over nodes

// ---------------- CSR build ----------------
__global__ void k_zero(int* __restrict__ p, int n) {
    int i = blockIdx.x * blockDim.x + threadIdx.x;
    if (i < n) p[i] = 0;
}

__global__ void k_count(const int* __restrict__ dst, int* __restrict__ cnt, int E) {
    int e = blockIdx.x * blockDim.x + threadIdx.x;
    if (e < E) atomicAdd(cnt + dst[e], 1);
}

__global__ __launch_bounds__(256) void k_scan1(const int* __restrict__ cnt, int* __restrict__ bsum) {
    __shared__ int s[256];
    const int t = threadIdx.x;
    const int i = blockIdx.x * 256 + t;
    s[t] = (i < N) ? cnt[i] : 0;
    __syncthreads();
    for (int off = 128; off > 0; off >>= 1) {
        if (t < off) s[t] += s[t + off];
        __syncthreads();
    }
    if (t == 0) bsum[blockIdx.x] = s[0];
}

__global__ __launch_bounds__(512) void k_scan2(const int* __restrict__ bsum, int* __restrict__ boff, int nb) {
    __shared__ int s[512];
    const int t = threadIdx.x;
    s[t] = (t < nb) ? bsum[t] : 0;
    __syncthreads();
    for (int off = 1; off < 512; off <<= 1) {
        int v = (t >= off) ? s[t - off] : 0;
        __syncthreads();
        s[t] += v;
        __syncthreads();
    }
    if (t < nb) boff[t] = (t == 0) ? 0 : s[t - 1];
}

__global__ __launch_bounds__(256) void k_scan3(const int* __restrict__ cnt, const int* __restrict__ boff,
                                               int* __restrict__ row_start, int* __restrict__ cursor) {
    __shared__ int s[256];
    const int t = threadIdx.x;
    const int i = blockIdx.x * 256 + t;
    const int v = (i < N) ? cnt[i] : 0;
    s[t] = v;
    __syncthreads();
    for (int off = 1; off < 256; off <<= 1) {
        int u = (t >= off) ? s[t - off] : 0;
        __syncthreads();
        s[t] += u;
        __syncthreads();
    }
    if (i < N) {
        int excl = s[t] - v + boff[blockIdx.x];
        row_start[i] = excl;
        cursor[i] = excl;
    }
}

__global__ void k_fill(const int* __restrict__ src, const int* __restrict__ dst,
                       int* __restrict__ cursor, int* __restrict__ col, int E) {
    int e = blockIdx.x * blockDim.x + threadIdx.x;
    if (e < E) {
        int p = atomicAdd(cursor + dst[e], 1);
        col[p] = src[e];
    }
}

// ---------------- layer 1 transform: g1 = dis * (x @ W1^T) ----------------
__global__ __launch_bounds__(256) void k_xw1(
        const float* __restrict__ x, const float* __restrict__ W1,
        const int* __restrict__ cnt, float* __restrict__ g1) {
    __shared__ float wt[128 * 33];   // W1 transposed [k][j], pad 33
    __shared__ float xs[8 * 128];
    const int t = threadIdx.x;
    for (int idx = t; idx < 4096; idx += 256) {
        int j = idx >> 7, k = idx & 127;
        wt[k * 33 + j] = W1[idx];
    }
    const float4* x4 = (const float4*)x + (size_t)blockIdx.x * 256;
    ((float4*)xs)[t] = x4[t];
    __syncthreads();

    const int nl = t >> 5, j = t & 31;
    const int node = blockIdx.x * 8 + nl;
    const float* xr = xs + nl * 128;
    float a = 0.f;
#pragma unroll 8
    for (int k = 0; k < 128; ++k) a = fmaf(xr[k], wt[k * 33 + j], a);
    g1[blockIdx.x * 256 + t] = a * rsqrtf((float)(cnt[node] + 1));
}

// ---------------- gather layer 1 ----------------
// 8 nodes / 256-thread block, 32 lanes per node. Branch-free unrolled inner
// loop: 32 independent gather loads in flight, 4 accumulators.
__global__ __launch_bounds__(256) void k_gather1(
        const int* __restrict__ row_start, const int* __restrict__ cnt,
        const int* __restrict__ col, const float* __restrict__ g1,
        const float* __restrict__ b1, float* __restrict__ h1) {
    const int t = threadIdx.x;
    const int node = blockIdx.x * 8 + (t >> 5);
    const int j = t & 31;
    const int rs = row_start[node];
    const int ne = cnt[node];
    float s0 = g1[node * 32 + j], s1 = 0.f, s2 = 0.f, s3 = 0.f;  // s0 seeded w/ self-loop
    for (int base = 0; base < ne; base += 32) {
        const int e = base + j;
        const int sv = (e < ne) ? col[rs + e] : 0;   // safe dummy = node 0
        const int rem = ne - base;
#pragma unroll
        for (int k = 0; k < 32; k += 4) {
            int i0 = __shfl(sv, k + 0, 32);
            int i1 = __shfl(sv, k + 1, 32);
            int i2 = __shfl(sv, k + 2, 32);
            int i3 = __shfl(sv, k + 3, 32);
            float w0 = (k + 0 < rem) ? 1.f : 0.f;
            float w1 = (k + 1 < rem) ? 1.f : 0.f;
            float w2 = (k + 2 < rem) ? 1.f : 0.f;
            float w3 = (k + 3 < rem) ? 1.f : 0.f;
            s0 = fmaf(w0, g1[i0 * 32 + j], s0);
            s1 = fmaf(w1, g1[i1 * 32 + j], s1);
            s2 = fmaf(w2, g1[i2 * 32 + j], s2);
            s3 = fmaf(w3, g1[i3 * 32 + j], s3);
        }
    }
    float sum = (s0 + s1) + (s2 + s3);
    float v = sum * rsqrtf((float)(ne + 1)) + b1[j];
    h1[node * 32 + j] = v > 0.f ? v : 0.f;
}

// ---------------- layer 2 transform: g2 = dis * (h1 @ W2^T) ----------------
__global__ __launch_bounds__(256) void k_layer2(
        const float* __restrict__ h1, const float* __restrict__ W2,
        const int* __restrict__ cnt, float* __restrict__ g2) {
    __shared__ float h1s[16 * 32];
    __shared__ float w2t[32 * 17];
    const int t = threadIdx.x;
    for (int idx = t; idx < 512; idx += 256) {
        int j = idx >> 5, k = idx & 31;
        w2t[k * 17 + j] = W2[idx];
    }
    const int base = blockIdx.x * 512;
    for (int idx = t; idx < 512; idx += 256) h1s[idx] = h1[base + idx];
    __syncthreads();
    const int nl = t >> 4, j = t & 15;
    const int node = blockIdx.x * 16 + nl;
    const float* hr = h1s + nl * 32;
    float a = 0.f;
#pragma unroll
    for (int k = 0; k < 32; ++k) a = fmaf(hr[k], w2t[k * 17 + j], a);
    g2[blockIdx.x * 256 + t] = a * rsqrtf((float)(cnt[node] + 1));
}

// ---------------- gather layer 2: h2 = relu(dis*(sum g2[src] + g2[node]) + b2) ----------------
// 16 nodes / 256-thread block, 16 lanes per node. Same branch-free unroll.
__global__ __launch_bounds__(256) void k_gather2(
        const int* __restrict__ row_start, const int* __restrict__ cnt,
        const int* __restrict__ col, const float* __restrict__ g2,
        const float* __restrict__ b2, float* __restrict__ h2) {
    const int t = threadIdx.x;
    const int node = blockIdx.x * 16 + (t >> 4);
    const int j = t & 15;
    const int rs = row_start[node];
    const int ne = cnt[node];
    float s0 = g2[node * 16 + j], s1 = 0.f, s2 = 0.f, s3 = 0.f;
    for (int base = 0; base < ne; base += 16) {
        const int e = base + j;
        const int sv = (e < ne) ? col[rs + e] : 0;
        const int rem = ne - base;
#pragma unroll
        for (int k = 0; k < 16; k += 4) {
            int i0 = __shfl(sv, k + 0, 16);
            int i1 = __shfl(sv, k + 1, 16);
            int i2 = __shfl(sv, k + 2, 16);
            int i3 = __shfl(sv, k + 3, 16);
            float w0 = (k + 0 < rem) ? 1.f : 0.f;
            float w1 = (k + 1 < rem) ? 1.f : 0.f;
            float w2 = (k + 2 < rem) ? 1.f : 0.f;
            float w3 = (k + 3 < rem) ? 1.f : 0.f;
            s0 = fmaf(w0, g2[i0 * 16 + j], s0);
            s1 = fmaf(w1, g2[i1 * 16 + j], s1);
            s2 = fmaf(w2, g2[i2 * 16 + j], s2);
            s3 = fmaf(w3, g2[i3 * 16 + j], s3);
        }
    }
    float sum = (s0 + s1) + (s2 + s3);
    float v = sum * rsqrtf((float)(ne + 1)) + b2[j];
    h2[node * 16 + j] = v > 0.f ? v : 0.f;
}

// ---------------- LSTM (h0=c0=0) + output head ----------------
__global__ __launch_bounds__(256) void k_final(
        const float* __restrict__ h2g,
        const float* __restrict__ w_ih, const float* __restrict__ b_ih,
        const float* __restrict__ b_hh, const float* __restrict__ W_out,
        const float* __restrict__ b_out, float* __restrict__ out) {
    __shared__ float wih[512];
    __shared__ float bias[32];
    __shared__ float wout[8];
    __shared__ float bo;
    const int t = threadIdx.x;
    for (int idx = t; idx < 512; idx += 256) wih[idx] = w_ih[idx];
    if (t < 32) bias[t] = b_ih[t] + b_hh[t];
    if (t < 8)  wout[t] = W_out[t];
    if (t == 0) bo = b_out[0];
    __syncthreads();

    const int i = blockIdx.x * 256 + t;
    if (i >= N) return;
    float h2[16];
    const float4* a4 = (const float4*)(h2g + (size_t)i * 16);
#pragma unroll
    for (int q = 0; q < 4; ++q) {
        float4 v = a4[q];
        h2[q * 4 + 0] = v.x; h2[q * 4 + 1] = v.y;
        h2[q * 4 + 2] = v.z; h2[q * 4 + 3] = v.w;
    }
    float oacc = 0.f;
#pragma unroll
    for (int q = 0; q < 8; ++q) {
        float gi = bias[q], gg = bias[16 + q], go = bias[24 + q];
#pragma unroll
        for (int k = 0; k < 16; ++k) {
            gi = fmaf(h2[k], wih[q * 16 + k], gi);
            gg = fmaf(h2[k], wih[(16 + q) * 16 + k], gg);
            go = fmaf(h2[k], wih[(24 + q) * 16 + k], go);
        }
        float c  = (1.f / (1.f + expf(-gi))) * tanhf(gg);
        float hh = (1.f / (1.f + expf(-go))) * tanhf(c);
        oacc = fmaf(hh, wout[q], oacc);
    }
    out[i] = oacc + bo;
}

extern "C" void kernel_launch(void* const* d_in, const int* in_sizes, int n_in,
                              void* d_out, int out_size, void* d_ws, size_t ws_size,
                              hipStream_t stream) {
    const float* x     = (const float*)d_in[0];
    const int*   ei    = (const int*)d_in[1];
    const float* W1    = (const float*)d_in[2];
    const float* b1    = (const float*)d_in[3];
    const float* W2    = (const float*)d_in[4];
    const float* b2    = (const float*)d_in[5];
    const float* w_ih  = (const float*)d_in[6];
    // d_in[7] = w_hh: unused (h0 = 0)
    const float* b_ih  = (const float*)d_in[8];
    const float* b_hh  = (const float*)d_in[9];
    const float* W_out = (const float*)d_in[10];
    const float* b_out = (const float*)d_in[11];
    float* out = (float*)d_out;

    const int E = in_sizes[1] / 2;
    const int* src = ei;
    const int* dst = ei + E;

    int* cnt       = (int*)d_ws;           // N
    int* row_start = cnt + N;              // N
    int* cursor    = row_start + N;        // N
    int* bsum      = cursor + N;           // 512
    int* boff      = bsum + 512;           // 512
    int* col       = boff + 512;           // E
    float* g1      = (float*)(col + E);    // N*32
    float* h1      = g1 + (size_t)N * 32;  // N*32
    float* g2      = g1;                   // overlay: g1 dead after k_gather1
    float* h2      = h1;                   // overlay: h1 dead after k_layer2

    k_zero   <<<NB, 256, 0, stream>>>(cnt, N);
    k_count  <<<(E + 255) / 256, 256, 0, stream>>>(dst, cnt, E);
    k_scan1  <<<NB, 256, 0, stream>>>(cnt, bsum);
    k_scan2  <<<1, 512, 0, stream>>>(bsum, boff, NB);
    k_scan3  <<<NB, 256, 0, stream>>>(cnt, boff, row_start, cursor);
    k_fill   <<<(E + 255) / 256, 256, 0, stream>>>(src, dst, cursor, col, E);
    k_xw1    <<<N / 8, 256, 0, stream>>>(x, W1, cnt, g1);
    k_gather1<<<N / 8, 256, 0, stream>>>(row_start, cnt, col, g1, b1, h1);
    k_layer2 <<<N / 16, 256, 0, stream>>>(h1, W2, cnt, g2);
    k_gather2<<<N / 16, 256, 0, stream>>>(row_start, cnt, col, g2, b2, h2);
    k_final  <<<NB, 256, 0, stream>>>(h2, w_ih, b_ih, b_hh, W_out, b_out, out);
}